// Round 11
// baseline (150.089 us; speedup 1.0000x reference)
//
#include <hip/hip_runtime.h>
#include <hip/hip_bf16.h>

#define NN 8192
#define DD 128

typedef short short8 __attribute__((ext_vector_type(8)));
typedef __bf16 bf16x8 __attribute__((ext_vector_type(8)));
typedef float f32x4 __attribute__((ext_vector_type(4)));

// unit-norm simplification (x2=y2=1):
//   d = 1 + c^2 - 2cs ;  q = nd^2 = 2c(1-s)/d ;  1-q = (1-c)^2/d exactly
//   rr = (1+nd)/(1-nd) = (1+nd)^2 * d/(1-c)^2
//   adc = -dist/T = KL*log2(rr) ; e = exp(adc) = exp2(KE*log2(rr))
#define MKc (-0.110803324099723f)   // -2c/(1-c)^2
#define PKc (0.110803324099723f)    // +2c/(1-c)^2
#define C1Kc (1.110803324099723f)   // (1+c^2)/(1-c)^2
#define KEc (-8.944271909999159f)   // -1/(sqrt_c*T)
#define KLc (-6.199696797323639f)   // KE*ln2

// ---------------- prep: normalize 16 rows/block -> bf16; zero accumulators ----------------
__global__ __launch_bounds__(256) void prep_kernel(const float* __restrict__ x,
                                                   __hip_bfloat16* __restrict__ fb,
                                                   float* __restrict__ totg,
                                                   float* __restrict__ tposg) {
  int r = threadIdx.x >> 4, sub = threadIdx.x & 15;
  int row = blockIdx.x * 16 + r;
  const float4 a = *(const float4*)(x + (size_t)row * DD + sub * 8);
  const float4 b = *(const float4*)(x + (size_t)row * DD + sub * 8 + 4);
  float ss = a.x * a.x + a.y * a.y + a.z * a.z + a.w * a.w +
             b.x * b.x + b.y * b.y + b.z * b.z + b.w * b.w;
  for (int off = 1; off < 16; off <<= 1) ss += __shfl_xor(ss, off, 16);
  float inv = 1.0f / fmaxf(sqrtf(ss), 1e-12f);
  float va[8] = {a.x, a.y, a.z, a.w, b.x, b.y, b.z, b.w};
  short8 h;
  for (int j = 0; j < 8; j++) {
    __hip_bfloat16 t = __float2bfloat16(va[j] * inv);
    h[j] = __builtin_bit_cast(short, t);
  }
  *(short8*)((short*)fb + (size_t)row * DD + sub * 8) = h;
  // zero the per-row accumulators (replaces memset nodes)
  if (threadIdx.x < 16) {
    totg[blockIdx.x * 16 + threadIdx.x] = 0.f;
    tposg[blockIdx.x * 16 + threadIdx.x] = 0.f;
  }
}

// ---------------- fused: 128 rows x 256 cols per block, no LDS staging, 8 blocks/CU ----------------
// B fragments load directly from global (fbg 2 MB, L2-resident; L1 absorbs
// intra-block redundancy). Keep launch_bounds(256,2): natural VGPR ~52 (A-frags
// land in unified AGPR file) -> full 8 waves/SIMD at grid 2048. Do NOT force
// min-waves>=4: that capped VGPR at 64 and spilled ~1GB in R8/R9.
__global__ __launch_bounds__(256, 2) void fused_kernel(
    const __hip_bfloat16* __restrict__ fbg,
    const int* __restrict__ plab, const int* __restrict__ slab,
    float* __restrict__ totg, float* __restrict__ tposg) {
  __shared__ int plc[256], slc[256];  // 2 KB: column labels

  const int tid = threadIdx.x;
  const int w = tid >> 6;
  const int lane = tid & 63;
  const int lrow = lane & 15;
  const int quad = lane >> 4;
  const int R0 = blockIdx.y * 128;
  const int C0 = blockIdx.x * 256;
  // diagonal present iff row range [R0,R0+128) intersects col range [C0,C0+256)
  const bool hasDiag = (blockIdx.y >> 1) == blockIdx.x;

  if (tid < 256) {
    plc[tid] = plab[C0 + tid];
    slc[tid] = slab[C0 + tid];
  }

  // A fragments + row labels (wave w owns rows R0 + w*32 .. +31, 2 strips of 16)
  bf16x8 af[2][4];
  int plr[2][4], slr[2][4];
  for (int strip = 0; strip < 2; strip++) {
    const short* fa = (const short*)fbg + (size_t)(R0 + w * 32 + strip * 16 + lrow) * DD;
    for (int kk = 0; kk < 4; kk++)
      af[strip][kk] = __builtin_bit_cast(bf16x8, *(const short8*)(fa + kk * 32 + quad * 8));
    for (int r = 0; r < 4; r++) {
      int rowg = R0 + w * 32 + strip * 16 + quad * 4 + r;
      plr[strip][r] = plab[rowg];
      slr[strip][r] = slab[rowg];
    }
  }
  __syncthreads();  // labels staged (the only barrier)

  float tot[2][4], lgs[2][4];
  for (int s_ = 0; s_ < 2; s_++)
    for (int r = 0; r < 4; r++) { tot[s_][r] = 0.f; lgs[s_][r] = 0.f; }

  for (int ct = 0; ct < 16; ct++) {
    const int lc = ct * 16 + lrow;
    const int colg = C0 + lc;
    const short* bp = (const short*)fbg + (size_t)colg * DD + quad * 8;
    bf16x8 bf[4];
    for (int kk = 0; kk < 4; kk++)
      bf[kk] = __builtin_bit_cast(bf16x8, *(const short8*)(bp + kk * 32));

    f32x4 acc[2];
    for (int strip = 0; strip < 2; strip++) {
      f32x4 a0 = {0.f, 0.f, 0.f, 0.f};
      for (int kk = 0; kk < 4; kk++)
        a0 = __builtin_amdgcn_mfma_f32_16x16x32_bf16(af[strip][kk], bf[kk], a0, 0, 0, 0);
      acc[strip] = a0;
    }
    const int pc = plc[lc];
    const int sc = slc[lc];
    if (hasDiag) {
      for (int strip = 0; strip < 2; strip++) {
        for (int r = 0; r < 4; r++) {
          float s = acc[strip][r];
          float tK = fmaxf(fmaf(s, MKc, PKc), 0.0f);
          float dk = fmaf(s, MKc, C1Kc);
          float m = fmaxf(tK * dk, 1e-30f);
          float nd = tK * __builtin_amdgcn_rsqf(m);
          float p1 = 1.0f + nd;
          float rr = p1 * p1 * dk;
          float lg = __log2f(rr);
          float e = exp2f(KEc * lg);
          int rowg = R0 + w * 32 + strip * 16 + quad * 4 + r;
          bool offd = (colg != rowg);
          bool same = (pc == plr[strip][r]) || (sc == slr[strip][r]);
          tot[strip][r] += offd ? e : 0.0f;
          lgs[strip][r] += (same && offd) ? lg : 0.0f;
        }
      }
    } else {
      for (int strip = 0; strip < 2; strip++) {
        for (int r = 0; r < 4; r++) {
          float s = acc[strip][r];
          float tK = fmaxf(fmaf(s, MKc, PKc), 0.0f);
          float dk = fmaf(s, MKc, C1Kc);
          float m = fmaxf(tK * dk, 1e-30f);
          float nd = tK * __builtin_amdgcn_rsqf(m);
          float p1 = 1.0f + nd;
          float rr = p1 * p1 * dk;
          float lg = __log2f(rr);
          float e = exp2f(KEc * lg);
          bool same = (pc == plr[strip][r]) || (sc == slr[strip][r]);
          tot[strip][r] += e;
          lgs[strip][r] += same ? lg : 0.0f;
        }
      }
    }
  }

  // 16-lane (column) reduce, per-row atomic partials
  for (int strip = 0; strip < 2; strip++) {
    for (int r = 0; r < 4; r++) {
      float t = tot[strip][r], g = lgs[strip][r];
      for (int off = 1; off < 16; off <<= 1) {
        t += __shfl_xor(t, off, 16);
        g += __shfl_xor(g, off, 16);
      }
      if (lrow == 0) {
        int rowg = R0 + w * 32 + strip * 16 + quad * 4 + r;
        atomicAdd(&totg[rowg], t);
        atomicAdd(&tposg[rowg], g);
      }
    }
  }
}

// ---------------- finalize: one 1024-thread block ----------------
__global__ __launch_bounds__(1024) void finalize_k(const float* __restrict__ totg,
                                                   const float* __restrict__ tposg,
                                                   const int* __restrict__ plab,
                                                   const int* __restrict__ slab,
                                                   float* __restrict__ out) {
  __shared__ int hist[512];
  __shared__ int cntP[32], cntS[16];
  __shared__ float redP[16], redV[16];
  const int tid = threadIdx.x;
  if (tid < 512) hist[tid] = 0;
  __syncthreads();
  for (int i = tid; i < NN; i += 1024)
    atomicAdd(&hist[plab[i] * 16 + slab[i]], 1);
  __syncthreads();
  if (tid < 32) {
    int s = 0;
    for (int j = 0; j < 16; j++) s += hist[tid * 16 + j];
    cntP[tid] = s;
  } else if (tid >= 64 && tid < 80) {
    int s = 0;
    for (int j = 0; j < 32; j++) s += hist[j * 16 + (tid - 64)];
    cntS[tid - 64] = s;
  }
  __syncthreads();
  float accP = 0.f, accV = 0.f;
  for (int i = tid; i < NN; i += 1024) {
    int pl = plab[i], sl = slab[i];
    int np = cntP[pl] + cntS[sl] - hist[pl * 16 + sl] - 1;
    if (np > 0) {
      accP += (KLc * tposg[i]) / (float)np - __logf(totg[i] + 1e-8f);
      accV += 1.f;
    }
  }
  for (int off = 32; off; off >>= 1) {
    accP += __shfl_xor(accP, off, 64);
    accV += __shfl_xor(accV, off, 64);
  }
  int wv = tid >> 6;
  if ((tid & 63) == 0) { redP[wv] = accP; redV[wv] = accV; }
  __syncthreads();
  if (tid == 0) {
    float sp = 0.f, sv = 0.f;
    for (int j = 0; j < 16; j++) { sp += redP[j]; sv += redV[j]; }
    float loss = -(sp / fmaxf(sv, 1.0f)) * 0.5f;  // * TEMPERATURE
    if (sv <= 0.0f || !__builtin_isfinite(loss)) loss = 0.0f;
    out[0] = loss;
  }
}

extern "C" void kernel_launch(void* const* d_in, const int* in_sizes, int n_in,
                              void* d_out, int out_size, void* d_ws, size_t ws_size,
                              hipStream_t stream) {
  const float* x = (const float*)d_in[0];
  const int* pl = (const int*)d_in[1];
  const int* sl = (const int*)d_in[2];
  char* ws = (char*)d_ws;
  __hip_bfloat16* fb = (__hip_bfloat16*)ws;    // 2,097,152 B
  float* totg = (float*)(ws + 2097152);        // 32 KB
  float* tposg = (float*)(ws + 2129920);       // 32 KB

  prep_kernel<<<NN / 16, 256, 0, stream>>>(x, fb, totg, tposg);
  fused_kernel<<<dim3(32, 64), 256, 0, stream>>>(fb, pl, sl, totg, tposg);
  finalize_k<<<1, 1024, 0, stream>>>(totg, tposg, pl, sl, (float*)d_out);
}

// Round 12
// 136.706 us; speedup vs baseline: 1.0979x; 1.0979x over previous
//
#include <hip/hip_runtime.h>
#include <hip/hip_bf16.h>

#define NN 8192
#define DD 128

typedef short short8 __attribute__((ext_vector_type(8)));
typedef __bf16 bf16x8 __attribute__((ext_vector_type(8)));
typedef float f32x4 __attribute__((ext_vector_type(4)));
typedef float f32x2 __attribute__((ext_vector_type(2)));

// unit-norm simplification (x2=y2=1):
//   d = 1 + c^2 - 2cs ;  q = nd^2 = 2c(1-s)/d ;  1-q = (1-c)^2/d exactly
//   rr = (1+nd)/(1-nd) = (1+nd)^2 * d/(1-c)^2
//   adc = -dist/T = KL*log2(rr) ; e = exp(adc) = exp2(KE*log2(rr))
#define MKc (-0.110803324099723f)   // -2c/(1-c)^2
#define PKc (0.110803324099723f)    // +2c/(1-c)^2
#define C1Kc (1.110803324099723f)   // (1+c^2)/(1-c)^2
#define KEc (-8.944271909999159f)   // -1/(sqrt_c*T)
#define KLc (-6.199696797323639f)   // KE*ln2

// ---------------- prep: normalize 16 rows/block -> bf16; zero accumulators ----------------
__global__ __launch_bounds__(256) void prep_kernel(const float* __restrict__ x,
                                                   __hip_bfloat16* __restrict__ fb,
                                                   float* __restrict__ totg,
                                                   float* __restrict__ tposg) {
  int r = threadIdx.x >> 4, sub = threadIdx.x & 15;
  int row = blockIdx.x * 16 + r;
  const float4 a = *(const float4*)(x + (size_t)row * DD + sub * 8);
  const float4 b = *(const float4*)(x + (size_t)row * DD + sub * 8 + 4);
  float ss = a.x * a.x + a.y * a.y + a.z * a.z + a.w * a.w +
             b.x * b.x + b.y * b.y + b.z * b.z + b.w * b.w;
  for (int off = 1; off < 16; off <<= 1) ss += __shfl_xor(ss, off, 16);
  float inv = 1.0f / fmaxf(sqrtf(ss), 1e-12f);
  float va[8] = {a.x, a.y, a.z, a.w, b.x, b.y, b.z, b.w};
  short8 h;
  for (int j = 0; j < 8; j++) {
    __hip_bfloat16 t = __float2bfloat16(va[j] * inv);
    h[j] = __builtin_bit_cast(short, t);
  }
  *(short8*)((short*)fb + (size_t)row * DD + sub * 8) = h;
  if (threadIdx.x < 16) {
    totg[blockIdx.x * 16 + threadIdx.x] = 0.f;
    tposg[blockIdx.x * 16 + threadIdx.x] = 0.f;
  }
}

// ---------------- fused: 128 rows x 512 cols per block (R10 config) + packed-fp32 elementwise ----------------
// B fragments direct from global (fbg 2 MB, L2-resident). launch_bounds(256,2):
// natural VGPR alloc, no spill (R8/R9: forcing min-waves=4 capped VGPR at 64 and
// spilled ~1GB scratch). Elementwise math done on float2 pairs so LLVM emits
// VOP3P packed fp32 (v_pk_fma_f32 etc.) -- halves full-rate VALU issue slots.
__global__ __launch_bounds__(256, 2) void fused_kernel(
    const __hip_bfloat16* __restrict__ fbg,
    const int* __restrict__ plab, const int* __restrict__ slab,
    float* __restrict__ totg, float* __restrict__ tposg) {
  __shared__ int plc[512], slc[512];  // 4 KB: column labels

  const int tid = threadIdx.x;
  const int w = tid >> 6;
  const int lane = tid & 63;
  const int lrow = lane & 15;
  const int quad = lane >> 4;
  const int R0 = blockIdx.y * 128;
  const int C0 = blockIdx.x * 512;
  // rows [R0,R0+128) vs cols [C0,C0+512): diagonal iff by/4 == bx
  const bool hasDiag = (blockIdx.y >> 2) == blockIdx.x;

  for (int i = tid; i < 512; i += 256) {
    plc[i] = plab[C0 + i];
    slc[i] = slab[C0 + i];
  }

  // A fragments + row labels (wave w owns rows R0 + w*32 .. +31, 2 strips of 16)
  bf16x8 af[2][4];
  int plr[2][4], slr[2][4];
  for (int strip = 0; strip < 2; strip++) {
    const short* fa = (const short*)fbg + (size_t)(R0 + w * 32 + strip * 16 + lrow) * DD;
    for (int kk = 0; kk < 4; kk++)
      af[strip][kk] = __builtin_bit_cast(bf16x8, *(const short8*)(fa + kk * 32 + quad * 8));
    for (int r = 0; r < 4; r++) {
      int rowg = R0 + w * 32 + strip * 16 + quad * 4 + r;
      plr[strip][r] = plab[rowg];
      slr[strip][r] = slab[rowg];
    }
  }
  __syncthreads();  // labels staged (the only barrier)

  const f32x2 MK2 = {MKc, MKc}, PK2 = {PKc, PKc}, C1K2 = {C1Kc, C1Kc};
  const f32x2 KE2 = {KEc, KEc}, ZERO2 = {0.f, 0.f}, EPS2 = {1e-30f, 1e-30f};
  const f32x2 ONE2 = {1.f, 1.f};

  // accumulators as float2 pairs: [strip][pair], pair p covers r = 2p, 2p+1
  f32x2 t2[2][2], g2[2][2];
  for (int s_ = 0; s_ < 2; s_++)
    for (int p = 0; p < 2; p++) { t2[s_][p] = ZERO2; g2[s_][p] = ZERO2; }

  // strength-reduced B pointer: column C0 + ct*16 + lrow
  const short* bp = (const short*)fbg + (size_t)(C0 + lrow) * DD + quad * 8;
  int colg = C0 + lrow;

  for (int ct = 0; ct < 32; ct++) {
    bf16x8 bf[4];
    for (int kk = 0; kk < 4; kk++)
      bf[kk] = __builtin_bit_cast(bf16x8, *(const short8*)(bp + kk * 32));
    bp += 16 * DD;

    f32x4 acc[2];
    for (int strip = 0; strip < 2; strip++) {
      f32x4 a0 = {0.f, 0.f, 0.f, 0.f};
      for (int kk = 0; kk < 4; kk++)
        a0 = __builtin_amdgcn_mfma_f32_16x16x32_bf16(af[strip][kk], bf[kk], a0, 0, 0, 0);
      acc[strip] = a0;
    }

    const int lc = ct * 16 + lrow;
    const int pc = plc[lc];
    const int sc = slc[lc];

    for (int strip = 0; strip < 2; strip++) {
      for (int p = 0; p < 2; p++) {
        f32x2 s2 = {acc[strip][2 * p], acc[strip][2 * p + 1]};
        f32x2 tK = __builtin_elementwise_fma(s2, MK2, PK2);
        tK = __builtin_elementwise_max(tK, ZERO2);
        f32x2 dk = __builtin_elementwise_fma(s2, MK2, C1K2);
        f32x2 m = __builtin_elementwise_max(tK * dk, EPS2);
        f32x2 rq = {__builtin_amdgcn_rsqf(m.x), __builtin_amdgcn_rsqf(m.y)};
        f32x2 nd = tK * rq;
        f32x2 p1 = nd + ONE2;
        f32x2 rr = p1 * p1 * dk;
        f32x2 lg = {__log2f(rr.x), __log2f(rr.y)};
        f32x2 el = KE2 * lg;
        f32x2 e = {exp2f(el.x), exp2f(el.y)};
        const int r0 = 2 * p, r1 = 2 * p + 1;
        bool same0 = (pc == plr[strip][r0]) || (sc == slr[strip][r0]);
        bool same1 = (pc == plr[strip][r1]) || (sc == slr[strip][r1]);
        if (hasDiag) {
          int rg0 = R0 + w * 32 + strip * 16 + quad * 4 + r0;
          bool off0 = (colg != rg0);
          bool off1 = (colg != rg0 + 1);
          f32x2 em = {off0 ? e.x : 0.f, off1 ? e.y : 0.f};
          f32x2 lm = {(same0 && off0) ? lg.x : 0.f, (same1 && off1) ? lg.y : 0.f};
          t2[strip][p] += em;
          g2[strip][p] += lm;
        } else {
          f32x2 lm = {same0 ? lg.x : 0.f, same1 ? lg.y : 0.f};
          t2[strip][p] += e;
          g2[strip][p] += lm;
        }
      }
    }
    colg += 16;
  }

  // 16-lane (column) reduce, per-row atomic partials
  for (int strip = 0; strip < 2; strip++) {
    for (int r = 0; r < 4; r++) {
      float t = t2[strip][r >> 1][r & 1];
      float g = g2[strip][r >> 1][r & 1];
      for (int off = 1; off < 16; off <<= 1) {
        t += __shfl_xor(t, off, 16);
        g += __shfl_xor(g, off, 16);
      }
      if (lrow == 0) {
        int rowg = R0 + w * 32 + strip * 16 + quad * 4 + r;
        atomicAdd(&totg[rowg], t);
        atomicAdd(&tposg[rowg], g);
      }
    }
  }
}

// ---------------- finalize: one 1024-thread block ----------------
__global__ __launch_bounds__(1024) void finalize_k(const float* __restrict__ totg,
                                                   const float* __restrict__ tposg,
                                                   const int* __restrict__ plab,
                                                   const int* __restrict__ slab,
                                                   float* __restrict__ out) {
  __shared__ int hist[512];
  __shared__ int cntP[32], cntS[16];
  __shared__ float redP[16], redV[16];
  const int tid = threadIdx.x;
  if (tid < 512) hist[tid] = 0;
  __syncthreads();
  for (int i = tid; i < NN; i += 1024)
    atomicAdd(&hist[plab[i] * 16 + slab[i]], 1);
  __syncthreads();
  if (tid < 32) {
    int s = 0;
    for (int j = 0; j < 16; j++) s += hist[tid * 16 + j];
    cntP[tid] = s;
  } else if (tid >= 64 && tid < 80) {
    int s = 0;
    for (int j = 0; j < 32; j++) s += hist[j * 16 + (tid - 64)];
    cntS[tid - 64] = s;
  }
  __syncthreads();
  float accP = 0.f, accV = 0.f;
  for (int i = tid; i < NN; i += 1024) {
    int pl = plab[i], sl = slab[i];
    int np = cntP[pl] + cntS[sl] - hist[pl * 16 + sl] - 1;
    if (np > 0) {
      accP += (KLc * tposg[i]) / (float)np - __logf(totg[i] + 1e-8f);
      accV += 1.f;
    }
  }
  for (int off = 32; off; off >>= 1) {
    accP += __shfl_xor(accP, off, 64);
    accV += __shfl_xor(accV, off, 64);
  }
  int wv = tid >> 6;
  if ((tid & 63) == 0) { redP[wv] = accP; redV[wv] = accV; }
  __syncthreads();
  if (tid == 0) {
    float sp = 0.f, sv = 0.f;
    for (int j = 0; j < 16; j++) { sp += redP[j]; sv += redV[j]; }
    float loss = -(sp / fmaxf(sv, 1.0f)) * 0.5f;  // * TEMPERATURE
    if (sv <= 0.0f || !__builtin_isfinite(loss)) loss = 0.0f;
    out[0] = loss;
  }
}

extern "C" void kernel_launch(void* const* d_in, const int* in_sizes, int n_in,
                              void* d_out, int out_size, void* d_ws, size_t ws_size,
                              hipStream_t stream) {
  const float* x = (const float*)d_in[0];
  const int* pl = (const int*)d_in[1];
  const int* sl = (const int*)d_in[2];
  char* ws = (char*)d_ws;
  __hip_bfloat16* fb = (__hip_bfloat16*)ws;    // 2,097,152 B
  float* totg = (float*)(ws + 2097152);        // 32 KB
  float* tposg = (float*)(ws + 2129920);       // 32 KB

  prep_kernel<<<NN / 16, 256, 0, stream>>>(x, fb, totg, tposg);
  fused_kernel<<<dim3(16, 64), 256, 0, stream>>>(fb, pl, sl, totg, tposg);
  finalize_k<<<1, 1024, 0, stream>>>(totg, tposg, pl, sl, (float*)d_out);
}

// Round 13
// 134.724 us; speedup vs baseline: 1.1140x; 1.0147x over previous
//
#include <hip/hip_runtime.h>
#include <hip/hip_bf16.h>

#define NN 8192
#define DD 128

typedef short short8 __attribute__((ext_vector_type(8)));
typedef __bf16 bf16x8 __attribute__((ext_vector_type(8)));
typedef float f32x4 __attribute__((ext_vector_type(4)));
typedef float f32x2 __attribute__((ext_vector_type(2)));

// unit-norm simplification (x2=y2=1):
//   d = 1 + c^2 - 2cs ;  q = nd^2 = 2c(1-s)/d ;  1-q = (1-c)^2/d exactly
//   rr = (1+nd)/(1-nd) = (1+nd)^2 * d/(1-c)^2
//   adc = -dist/T = KL*log2(rr) ; e = exp(adc) = exp2(KE*log2(rr))
#define MKc (-0.110803324099723f)   // -2c/(1-c)^2
#define PKc (0.110803324099723f)    // +2c/(1-c)^2
#define C1Kc (1.110803324099723f)   // (1+c^2)/(1-c)^2
#define KEc (-8.944271909999159f)   // -1/(sqrt_c*T)
#define KLc (-6.199696797323639f)   // KE*ln2

// ---------------- prep: normalize 16 rows/block -> bf16; zero accumulators ----------------
__global__ __launch_bounds__(256) void prep_kernel(const float* __restrict__ x,
                                                   __hip_bfloat16* __restrict__ fb,
                                                   float* __restrict__ totg,
                                                   float* __restrict__ tposg) {
  int r = threadIdx.x >> 4, sub = threadIdx.x & 15;
  int row = blockIdx.x * 16 + r;
  const float4 a = *(const float4*)(x + (size_t)row * DD + sub * 8);
  const float4 b = *(const float4*)(x + (size_t)row * DD + sub * 8 + 4);
  float ss = a.x * a.x + a.y * a.y + a.z * a.z + a.w * a.w +
             b.x * b.x + b.y * b.y + b.z * b.z + b.w * b.w;
  for (int off = 1; off < 16; off <<= 1) ss += __shfl_xor(ss, off, 16);
  float inv = 1.0f / fmaxf(sqrtf(ss), 1e-12f);
  float va[8] = {a.x, a.y, a.z, a.w, b.x, b.y, b.z, b.w};
  short8 h;
  for (int j = 0; j < 8; j++) {
    __hip_bfloat16 t = __float2bfloat16(va[j] * inv);
    h[j] = __builtin_bit_cast(short, t);
  }
  *(short8*)((short*)fb + (size_t)row * DD + sub * 8) = h;
  if (threadIdx.x < 16) {
    totg[blockIdx.x * 16 + threadIdx.x] = 0.f;
    tposg[blockIdx.x * 16 + threadIdx.x] = 0.f;
  }
}

// ---------------- fused: 256 rows x 512 cols per block, direct-global B + prefetch ----------------
// R5's 256-row reuse (each B-fragment feeds 16 MFMAs; prologue amortized 2x vs
// 128-row) + R10's no-LDS/no-barrier B path + R12's packed-f32 elementwise +
// explicit next-iteration B prefetch to hide L1/L2 load latency.
// launch_bounds(256,2): natural VGPR (R5: 128, zero spill). NEVER (256,4):
// forced 64-VGPR cap -> ~1GB scratch spill (R7/R8/R9 post-mortems).
__global__ __launch_bounds__(256, 2) void fused_kernel(
    const __hip_bfloat16* __restrict__ fbg,
    const int* __restrict__ plab, const int* __restrict__ slab,
    float* __restrict__ totg, float* __restrict__ tposg) {
  __shared__ int plc[512], slc[512];  // 4 KB: column labels

  const int tid = threadIdx.x;
  const int w = tid >> 6;
  const int lane = tid & 63;
  const int lrow = lane & 15;
  const int quad = lane >> 4;
  const int R0 = blockIdx.y * 256;
  const int C0 = blockIdx.x * 512;
  // rows [R0,R0+256) vs cols [C0,C0+512): diagonal iff by/2 == bx
  const bool hasDiag = (blockIdx.y >> 1) == blockIdx.x;

  for (int i = tid; i < 512; i += 256) {
    plc[i] = plab[C0 + i];
    slc[i] = slab[C0 + i];
  }

  // A fragments + row labels (wave w owns rows R0 + w*64 .. +63, 4 strips of 16)
  bf16x8 af[4][4];
  int plr[4][4], slr[4][4];
  for (int strip = 0; strip < 4; strip++) {
    const short* fa = (const short*)fbg + (size_t)(R0 + w * 64 + strip * 16 + lrow) * DD;
    for (int kk = 0; kk < 4; kk++)
      af[strip][kk] = __builtin_bit_cast(bf16x8, *(const short8*)(fa + kk * 32 + quad * 8));
    for (int r = 0; r < 4; r++) {
      int rowg = R0 + w * 64 + strip * 16 + quad * 4 + r;
      plr[strip][r] = plab[rowg];
      slr[strip][r] = slab[rowg];
    }
  }
  __syncthreads();  // labels staged (the only barrier)

  const f32x2 MK2 = {MKc, MKc}, PK2 = {PKc, PKc}, C1K2 = {C1Kc, C1Kc};
  const f32x2 KE2 = {KEc, KEc}, ZERO2 = {0.f, 0.f}, EPS2 = {1e-30f, 1e-30f};
  const f32x2 ONE2 = {1.f, 1.f};

  // accumulators as float2 pairs: [strip][pair], pair p covers r = 2p, 2p+1
  f32x2 t2[4][2], g2[4][2];
  for (int s_ = 0; s_ < 4; s_++)
    for (int p = 0; p < 2; p++) { t2[s_][p] = ZERO2; g2[s_][p] = ZERO2; }

  // strength-reduced B pointer; prefetch first group
  const short* bp = (const short*)fbg + (size_t)(C0 + lrow) * DD + quad * 8;
  bf16x8 bf[4];
  for (int kk = 0; kk < 4; kk++)
    bf[kk] = __builtin_bit_cast(bf16x8, *(const short8*)(bp + kk * 32));
  int colg = C0 + lrow;

  for (int ct = 0; ct < 32; ct++) {
    // prefetch next ct's B fragments (independent of current compute; the
    // final iteration reads <=8KB past fb into the ws accumulator region --
    // allocated memory, result discarded)
    const short* bpn = bp + 16 * DD;
    bf16x8 bn[4];
    for (int kk = 0; kk < 4; kk++)
      bn[kk] = __builtin_bit_cast(bf16x8, *(const short8*)(bpn + kk * 32));

    f32x4 acc[4];
    for (int strip = 0; strip < 4; strip++) {
      f32x4 a0 = {0.f, 0.f, 0.f, 0.f};
      for (int kk = 0; kk < 4; kk++)
        a0 = __builtin_amdgcn_mfma_f32_16x16x32_bf16(af[strip][kk], bf[kk], a0, 0, 0, 0);
      acc[strip] = a0;
    }

    const int lc = ct * 16 + lrow;
    const int pc = plc[lc];
    const int sc = slc[lc];

    for (int strip = 0; strip < 4; strip++) {
      for (int p = 0; p < 2; p++) {
        f32x2 s2 = {acc[strip][2 * p], acc[strip][2 * p + 1]};
        f32x2 tK = __builtin_elementwise_fma(s2, MK2, PK2);
        tK = __builtin_elementwise_max(tK, ZERO2);
        f32x2 dk = __builtin_elementwise_fma(s2, MK2, C1K2);
        f32x2 m = __builtin_elementwise_max(tK * dk, EPS2);
        f32x2 rq = {__builtin_amdgcn_rsqf(m.x), __builtin_amdgcn_rsqf(m.y)};
        f32x2 nd = tK * rq;
        f32x2 p1 = nd + ONE2;
        f32x2 rr = p1 * p1 * dk;
        f32x2 lg = {__log2f(rr.x), __log2f(rr.y)};
        f32x2 el = KE2 * lg;
        f32x2 e = {exp2f(el.x), exp2f(el.y)};
        const int r0 = 2 * p, r1 = 2 * p + 1;
        bool same0 = (pc == plr[strip][r0]) || (sc == slr[strip][r0]);
        bool same1 = (pc == plr[strip][r1]) || (sc == slr[strip][r1]);
        if (hasDiag) {
          int rg0 = R0 + w * 64 + strip * 16 + quad * 4 + r0;
          bool off0 = (colg != rg0);
          bool off1 = (colg != rg0 + 1);
          f32x2 em = {off0 ? e.x : 0.f, off1 ? e.y : 0.f};
          f32x2 lm = {(same0 && off0) ? lg.x : 0.f, (same1 && off1) ? lg.y : 0.f};
          t2[strip][p] += em;
          g2[strip][p] += lm;
        } else {
          f32x2 lm = {same0 ? lg.x : 0.f, same1 ? lg.y : 0.f};
          t2[strip][p] += e;
          g2[strip][p] += lm;
        }
      }
    }
    for (int kk = 0; kk < 4; kk++) bf[kk] = bn[kk];
    bp = bpn;
    colg += 16;
  }

  // 16-lane (column) reduce, per-row atomic partials
  for (int strip = 0; strip < 4; strip++) {
    for (int r = 0; r < 4; r++) {
      float t = t2[strip][r >> 1][r & 1];
      float g = g2[strip][r >> 1][r & 1];
      for (int off = 1; off < 16; off <<= 1) {
        t += __shfl_xor(t, off, 16);
        g += __shfl_xor(g, off, 16);
      }
      if (lrow == 0) {
        int rowg = R0 + w * 64 + strip * 16 + quad * 4 + r;
        atomicAdd(&totg[rowg], t);
        atomicAdd(&tposg[rowg], g);
      }
    }
  }
}

// ---------------- finalize: one 1024-thread block ----------------
__global__ __launch_bounds__(1024) void finalize_k(const float* __restrict__ totg,
                                                   const float* __restrict__ tposg,
                                                   const int* __restrict__ plab,
                                                   const int* __restrict__ slab,
                                                   float* __restrict__ out) {
  __shared__ int hist[512];
  __shared__ int cntP[32], cntS[16];
  __shared__ float redP[16], redV[16];
  const int tid = threadIdx.x;
  if (tid < 512) hist[tid] = 0;
  __syncthreads();
  for (int i = tid; i < NN; i += 1024)
    atomicAdd(&hist[plab[i] * 16 + slab[i]], 1);
  __syncthreads();
  if (tid < 32) {
    int s = 0;
    for (int j = 0; j < 16; j++) s += hist[tid * 16 + j];
    cntP[tid] = s;
  } else if (tid >= 64 && tid < 80) {
    int s = 0;
    for (int j = 0; j < 32; j++) s += hist[j * 16 + (tid - 64)];
    cntS[tid - 64] = s;
  }
  __syncthreads();
  float accP = 0.f, accV = 0.f;
  for (int i = tid; i < NN; i += 1024) {
    int pl = plab[i], sl = slab[i];
    int np = cntP[pl] + cntS[sl] - hist[pl * 16 + sl] - 1;
    if (np > 0) {
      accP += (KLc * tposg[i]) / (float)np - __logf(totg[i] + 1e-8f);
      accV += 1.f;
    }
  }
  for (int off = 32; off; off >>= 1) {
    accP += __shfl_xor(accP, off, 64);
    accV += __shfl_xor(accV, off, 64);
  }
  int wv = tid >> 6;
  if ((tid & 63) == 0) { redP[wv] = accP; redV[wv] = accV; }
  __syncthreads();
  if (tid == 0) {
    float sp = 0.f, sv = 0.f;
    for (int j = 0; j < 16; j++) { sp += redP[j]; sv += redV[j]; }
    float loss = -(sp / fmaxf(sv, 1.0f)) * 0.5f;  // * TEMPERATURE
    if (sv <= 0.0f || !__builtin_isfinite(loss)) loss = 0.0f;
    out[0] = loss;
  }
}

extern "C" void kernel_launch(void* const* d_in, const int* in_sizes, int n_in,
                              void* d_out, int out_size, void* d_ws, size_t ws_size,
                              hipStream_t stream) {
  const float* x = (const float*)d_in[0];
  const int* pl = (const int*)d_in[1];
  const int* sl = (const int*)d_in[2];
  char* ws = (char*)d_ws;
  __hip_bfloat16* fb = (__hip_bfloat16*)ws;    // 2,097,152 B
  float* totg = (float*)(ws + 2097152);        // 32 KB
  float* tposg = (float*)(ws + 2129920);       // 32 KB

  prep_kernel<<<NN / 16, 256, 0, stream>>>(x, fb, totg, tposg);
  fused_kernel<<<dim3(16, 32), 256, 0, stream>>>(fb, pl, sl, totg, tposg);
  finalize_k<<<1, 1024, 0, stream>>>(totg, tposg, pl, sl, (float*)d_out);
}

// Round 14
// 123.811 us; speedup vs baseline: 1.2122x; 1.0881x over previous
//
#include <hip/hip_runtime.h>
#include <hip/hip_bf16.h>

#define NN 8192
#define DD 128

typedef short short8 __attribute__((ext_vector_type(8)));
typedef __bf16 bf16x8 __attribute__((ext_vector_type(8)));
typedef float f32x4 __attribute__((ext_vector_type(4)));
typedef float f32x2 __attribute__((ext_vector_type(2)));

// unit-norm simplification (x2=y2=1):
//   d = 1 + c^2 - 2cs ;  q = nd^2 = 2c(1-s)/d ;  1-q = (1-c)^2/d exactly
//   rr = (1+nd)/(1-nd) = (1+nd)^2 * d/(1-c)^2
//   adc = -dist/T = KL*log2(rr) ; e = exp(adc) = exp2(KE*log2(rr))
// s is symmetric (unit norms) and the label mask is symmetric, so each
// unordered pair {i,j}, i>j is computed ONCE and credited to row i and col j.
#define MKc (-0.110803324099723f)   // -2c/(1-c)^2
#define PKc (0.110803324099723f)    // +2c/(1-c)^2
#define C1Kc (1.110803324099723f)   // (1+c^2)/(1-c)^2
#define KEc (-8.944271909999159f)   // -1/(sqrt_c*T)
#define KLc (-6.199696797323639f)   // KE*ln2

// ---------------- prep: normalize 16 rows/block -> bf16; zero accumulators ----------------
__global__ __launch_bounds__(256) void prep_kernel(const float* __restrict__ x,
                                                   __hip_bfloat16* __restrict__ fb,
                                                   float* __restrict__ totg,
                                                   float* __restrict__ tposg) {
  int r = threadIdx.x >> 4, sub = threadIdx.x & 15;
  int row = blockIdx.x * 16 + r;
  const float4 a = *(const float4*)(x + (size_t)row * DD + sub * 8);
  const float4 b = *(const float4*)(x + (size_t)row * DD + sub * 8 + 4);
  float ss = a.x * a.x + a.y * a.y + a.z * a.z + a.w * a.w +
             b.x * b.x + b.y * b.y + b.z * b.z + b.w * b.w;
  for (int off = 1; off < 16; off <<= 1) ss += __shfl_xor(ss, off, 16);
  float inv = 1.0f / fmaxf(sqrtf(ss), 1e-12f);
  float va[8] = {a.x, a.y, a.z, a.w, b.x, b.y, b.z, b.w};
  short8 h;
  for (int j = 0; j < 8; j++) {
    __hip_bfloat16 t = __float2bfloat16(va[j] * inv);
    h[j] = __builtin_bit_cast(short, t);
  }
  *(short8*)((short*)fb + (size_t)row * DD + sub * 8) = h;
  if (threadIdx.x < 16) {
    totg[blockIdx.x * 16 + threadIdx.x] = 0.f;
    tposg[blockIdx.x * 16 + threadIdx.x] = 0.f;
  }
}

// ---------------- fused symmetric: 128 rows x 512 cols, lower-triangle blocks only ----------------
// Block list: (I,J), I in [4J, 64), J in [0,16). 544 blocks. I>=4J+4: fully
// lower (no mask); I<=4J+3: straddle, strict col<row mask. Row credit via
// registers (R12 path); col credit via per-wave LDS accumulators, flushed once
// per block. launch_bounds(256,2): natural VGPR, no spill (NEVER (256,4):
// 64-VGPR cap -> ~1GB scratch spill, R7/R8/R9).
__global__ __launch_bounds__(256, 2) void fused_kernel(
    const __hip_bfloat16* __restrict__ fbg,
    const int* __restrict__ plab, const int* __restrict__ slab,
    float* __restrict__ totg, float* __restrict__ tposg) {
  __shared__ int plc[512], slc[512];          // 4 KB: column labels
  __shared__ float colT_l[4 * 512];           // 8 KB: per-wave col e-sums
  __shared__ float colG_l[4 * 512];           // 8 KB: per-wave col lg-sums

  const int tid = threadIdx.x;
  const int w = tid >> 6;
  const int lane = tid & 63;
  const int lrow = lane & 15;
  const int quad = lane >> 4;

  // decode (I,J) from linear block id: J groups of (64-4J) blocks
  int J = 0, rem = blockIdx.x;
  while (rem >= 64 - 4 * J) { rem -= 64 - 4 * J; J++; }
  const int I = 4 * J + rem;
  const bool needMask = (I < 4 * J + 4);  // straddles the diagonal
  const int R0 = I * 128;
  const int C0 = J * 512;

  for (int i = tid; i < 512; i += 256) {
    plc[i] = plab[C0 + i];
    slc[i] = slab[C0 + i];
  }
  // each wave zeroes its own col-accumulator region (no cross-wave hazard)
  for (int i = lane; i < 512; i += 64) {
    colT_l[w * 512 + i] = 0.f;
    colG_l[w * 512 + i] = 0.f;
  }

  // A fragments + row labels (wave w owns rows R0 + w*32 .. +31, 2 strips of 16)
  bf16x8 af[2][4];
  int plr[2][4], slr[2][4];
  for (int strip = 0; strip < 2; strip++) {
    const short* fa = (const short*)fbg + (size_t)(R0 + w * 32 + strip * 16 + lrow) * DD;
    for (int kk = 0; kk < 4; kk++)
      af[strip][kk] = __builtin_bit_cast(bf16x8, *(const short8*)(fa + kk * 32 + quad * 8));
    for (int r = 0; r < 4; r++) {
      int rowg = R0 + w * 32 + strip * 16 + quad * 4 + r;
      plr[strip][r] = plab[rowg];
      slr[strip][r] = slab[rowg];
    }
  }
  __syncthreads();  // labels staged

  const f32x2 MK2 = {MKc, MKc}, PK2 = {PKc, PKc}, C1K2 = {C1Kc, C1Kc};
  const f32x2 KE2 = {KEc, KEc}, ZERO2 = {0.f, 0.f}, EPS2 = {1e-30f, 1e-30f};
  const f32x2 ONE2 = {1.f, 1.f};

  f32x2 t2[2][2], g2[2][2];
  for (int s_ = 0; s_ < 2; s_++)
    for (int p = 0; p < 2; p++) { t2[s_][p] = ZERO2; g2[s_][p] = ZERO2; }

  const short* bp = (const short*)fbg + (size_t)(C0 + lrow) * DD + quad * 8;
  int colg = C0 + lrow;

  for (int ct = 0; ct < 32; ct++) {
    bf16x8 bf[4];
    for (int kk = 0; kk < 4; kk++)
      bf[kk] = __builtin_bit_cast(bf16x8, *(const short8*)(bp + kk * 32));
    bp += 16 * DD;

    f32x4 acc[2];
    for (int strip = 0; strip < 2; strip++) {
      f32x4 a0 = {0.f, 0.f, 0.f, 0.f};
      for (int kk = 0; kk < 4; kk++)
        a0 = __builtin_amdgcn_mfma_f32_16x16x32_bf16(af[strip][kk], bf[kk], a0, 0, 0, 0);
      acc[strip] = a0;
    }

    const int lc = ct * 16 + lrow;
    const int pc = plc[lc];
    const int sc = slc[lc];

    f32x2 colE = ZERO2, colL = ZERO2;  // this lane's col credit (one col per lane)

    for (int strip = 0; strip < 2; strip++) {
      for (int p = 0; p < 2; p++) {
        f32x2 s2 = {acc[strip][2 * p], acc[strip][2 * p + 1]};
        f32x2 tK = __builtin_elementwise_fma(s2, MK2, PK2);
        tK = __builtin_elementwise_max(tK, ZERO2);
        f32x2 dk = __builtin_elementwise_fma(s2, MK2, C1K2);
        f32x2 m = __builtin_elementwise_max(tK * dk, EPS2);
        f32x2 rq = {__builtin_amdgcn_rsqf(m.x), __builtin_amdgcn_rsqf(m.y)};
        f32x2 nd = tK * rq;
        f32x2 p1 = nd + ONE2;
        f32x2 rr = p1 * p1 * dk;
        f32x2 lg = {__log2f(rr.x), __log2f(rr.y)};
        f32x2 el = KE2 * lg;
        f32x2 e = {exp2f(el.x), exp2f(el.y)};
        const int r0 = 2 * p, r1 = 2 * p + 1;
        bool same0 = (pc == plr[strip][r0]) || (sc == slr[strip][r0]);
        bool same1 = (pc == plr[strip][r1]) || (sc == slr[strip][r1]);
        f32x2 em, lm;
        if (needMask) {
          int rg0 = R0 + w * 32 + strip * 16 + quad * 4 + r0;
          bool ok0 = (colg < rg0);
          bool ok1 = (colg < rg0 + 1);
          em.x = ok0 ? e.x : 0.f;
          em.y = ok1 ? e.y : 0.f;
          lm.x = (same0 && ok0) ? lg.x : 0.f;
          lm.y = (same1 && ok1) ? lg.y : 0.f;
        } else {
          em = e;
          lm.x = same0 ? lg.x : 0.f;
          lm.y = same1 ? lg.y : 0.f;
        }
        t2[strip][p] += em;
        g2[strip][p] += lm;
        colE += em;
        colL += lm;
      }
    }

    // col credit: reduce across the 4 quads (rows), accumulate in this wave's LDS region
    float cE = colE.x + colE.y;
    float cL = colL.x + colL.y;
    cE += __shfl_xor(cE, 16, 64);
    cE += __shfl_xor(cE, 32, 64);
    cL += __shfl_xor(cL, 16, 64);
    cL += __shfl_xor(cL, 32, 64);
    if (quad == 0) {
      colT_l[w * 512 + lc] += cE;
      colG_l[w * 512 + lc] += cL;
    }
    colg += 16;
  }

  // row-side: 16-lane reduce, per-row atomics
  for (int strip = 0; strip < 2; strip++) {
    for (int r = 0; r < 4; r++) {
      float t = t2[strip][r >> 1][r & 1];
      float g = g2[strip][r >> 1][r & 1];
      for (int off = 1; off < 16; off <<= 1) {
        t += __shfl_xor(t, off, 16);
        g += __shfl_xor(g, off, 16);
      }
      if (lrow == 0) {
        int rowg = R0 + w * 32 + strip * 16 + quad * 4 + r;
        atomicAdd(&totg[rowg], t);
        atomicAdd(&tposg[rowg], g);
      }
    }
  }

  // col-side: combine the 4 wave regions, one atomic per col per block
  __syncthreads();
  for (int i = tid; i < 512; i += 256) {
    float sE = colT_l[i] + colT_l[512 + i] + colT_l[1024 + i] + colT_l[1536 + i];
    float sL = colG_l[i] + colG_l[512 + i] + colG_l[1024 + i] + colG_l[1536 + i];
    atomicAdd(&totg[C0 + i], sE);
    atomicAdd(&tposg[C0 + i], sL);
  }
}

// ---------------- finalize: one 1024-thread block ----------------
__global__ __launch_bounds__(1024) void finalize_k(const float* __restrict__ totg,
                                                   const float* __restrict__ tposg,
                                                   const int* __restrict__ plab,
                                                   const int* __restrict__ slab,
                                                   float* __restrict__ out) {
  __shared__ int hist[512];
  __shared__ int cntP[32], cntS[16];
  __shared__ float redP[16], redV[16];
  const int tid = threadIdx.x;
  if (tid < 512) hist[tid] = 0;
  __syncthreads();
  for (int i = tid; i < NN; i += 1024)
    atomicAdd(&hist[plab[i] * 16 + slab[i]], 1);
  __syncthreads();
  if (tid < 32) {
    int s = 0;
    for (int j = 0; j < 16; j++) s += hist[tid * 16 + j];
    cntP[tid] = s;
  } else if (tid >= 64 && tid < 80) {
    int s = 0;
    for (int j = 0; j < 32; j++) s += hist[j * 16 + (tid - 64)];
    cntS[tid - 64] = s;
  }
  __syncthreads();
  float accP = 0.f, accV = 0.f;
  for (int i = tid; i < NN; i += 1024) {
    int pl = plab[i], sl = slab[i];
    int np = cntP[pl] + cntS[sl] - hist[pl * 16 + sl] - 1;
    if (np > 0) {
      accP += (KLc * tposg[i]) / (float)np - __logf(totg[i] + 1e-8f);
      accV += 1.f;
    }
  }
  for (int off = 32; off; off >>= 1) {
    accP += __shfl_xor(accP, off, 64);
    accV += __shfl_xor(accV, off, 64);
  }
  int wv = tid >> 6;
  if ((tid & 63) == 0) { redP[wv] = accP; redV[wv] = accV; }
  __syncthreads();
  if (tid == 0) {
    float sp = 0.f, sv = 0.f;
    for (int j = 0; j < 16; j++) { sp += redP[j]; sv += redV[j]; }
    float loss = -(sp / fmaxf(sv, 1.0f)) * 0.5f;  // * TEMPERATURE
    if (sv <= 0.0f || !__builtin_isfinite(loss)) loss = 0.0f;
    out[0] = loss;
  }
}

extern "C" void kernel_launch(void* const* d_in, const int* in_sizes, int n_in,
                              void* d_out, int out_size, void* d_ws, size_t ws_size,
                              hipStream_t stream) {
  const float* x = (const float*)d_in[0];
  const int* pl = (const int*)d_in[1];
  const int* sl = (const int*)d_in[2];
  char* ws = (char*)d_ws;
  __hip_bfloat16* fb = (__hip_bfloat16*)ws;    // 2,097,152 B
  float* totg = (float*)(ws + 2097152);        // 32 KB
  float* tposg = (float*)(ws + 2129920);       // 32 KB

  prep_kernel<<<NN / 16, 256, 0, stream>>>(x, fb, totg, tposg);
  fused_kernel<<<544, 256, 0, stream>>>(fb, pl, sl, totg, tposg);
  finalize_k<<<1, 1024, 0, stream>>>(totg, tposg, pl, sl, (float*)d_out);
}